// Round 3
// baseline (381.716 us; speedup 1.0000x reference)
//
#include <hip/hip_runtime.h>
#include <hip/hip_bf16.h>
#include <cmath>

// Problem constants (from reference)
#define NTOK 4096      // B*T
#define Dm   512
#define Hm   1024
#define Cm   32
#define Km   3
#define NEVm 50
#define NGm  6
#define NBANK 14       // 2 shared + 12 group banks
#define Em   4         // S+G
#define MAXMT 144      // worst-case m-tiles (128-token tiles): 64 shared + <=76 group

typedef __bf16 bf16x8 __attribute__((ext_vector_type(8)));
typedef float  floatx4 __attribute__((ext_vector_type(4)));

// ---------------------------------------------------------------- prep
// bucket tokens by group (wave-aggregated atomics) + build compact tile table
__global__ __launch_bounds__(1024) void k_prep(
    const int* __restrict__ ids, const int* __restrict__ e2g,
    int* __restrict__ gids, int* __restrict__ counts,
    int* __restrict__ lists, int2* __restrict__ table, int* __restrict__ ntot)
{
    __shared__ int lcnt[NGm];
    const int t = threadIdx.x;
    const int lane = t & 63;
    if (t < NGm) lcnt[t] = 0;
    __syncthreads();
    for (int n = t; n < NTOK; n += 1024) {
        int id = ids[n];
        id = id < 0 ? 0 : (id > NEVm - 1 ? NEVm - 1 : id);
        int g = e2g[id];
        gids[n] = g;
        int pos = 0;
        #pragma unroll
        for (int gg = 0; gg < NGm; gg++) {
            unsigned long long m = __ballot(g == gg);
            if (g == gg) {
                int leader = __ffsll((unsigned long long)m) - 1;
                int base = 0;
                if (lane == leader) base = atomicAdd(&lcnt[gg], (int)__popcll(m));
                base = __shfl(base, leader, 64);
                pos = base + (int)__popcll(m & ((1ull << lane) - 1));
            }
        }
        lists[g * NTOK + pos] = n;
    }
    __syncthreads();
    if (t < NGm) counts[t] = lcnt[t];
    if (t == 0) {
        int idx = 0;
        for (int b = 0; b < 2; b++)
            for (int m0 = 0; m0 < NTOK; m0 += 128) table[idx++] = make_int2(b, m0);
        for (int g = 0; g < NGm; g++) {
            int c = lcnt[g];
            for (int gg = 0; gg < 2; gg++) {
                int bank = 2 + 2 * g + gg;
                for (int m0 = 0; m0 < c; m0 += 128) table[idx++] = make_int2(bank, m0);
            }
        }
        *ntot = idx;
    }
}

// fp32 -> bf16 elementwise
__global__ void k_cvt(const float* __restrict__ in, __bf16* __restrict__ out, int n) {
    int i = (blockIdx.x * 256 + threadIdx.x) * 8;
    if (i >= n) return;
    float4 a = *(const float4*)(in + i);
    float4 b = *(const float4*)(in + i + 4);
    bf16x8 v;
    v[0] = (__bf16)a.x; v[1] = (__bf16)a.y; v[2] = (__bf16)a.z; v[3] = (__bf16)a.w;
    v[4] = (__bf16)b.x; v[5] = (__bf16)b.y; v[6] = (__bf16)b.z; v[7] = (__bf16)b.w;
    *(bf16x8*)(out + i) = v;
}

// all four weight transposes in ONE dispatch.
// W1 set: 14 banks x (512x1024) -> [1024][512]; W2 set: 14 x (1024x512) -> [512][1024]
// grid 3584 blocks x 256
__global__ __launch_bounds__(256) void k_trans_all(
    const float* __restrict__ Ws1, const float* __restrict__ Wg1,
    const float* __restrict__ Ws2, const float* __restrict__ Wg2,
    __bf16* __restrict__ W1t, __bf16* __restrict__ W2t)
{
    __shared__ float tile[64][65];
    int idx = blockIdx.x;
    const float* in; __bf16* out; int C, cshift, tile_i;
    const size_t HD = (size_t)Hm * Dm;
    if (idx < 1792) {
        int bank = idx >> 7; tile_i = idx & 127;
        C = Hm; cshift = 4;
        in = (bank < 2) ? (Ws1 + (size_t)bank * HD) : (Wg1 + (size_t)(bank - 2) * HD);
        out = W1t + (size_t)bank * HD;
    } else {
        idx -= 1792;
        int bank = idx >> 7; tile_i = idx & 127;
        C = Dm; cshift = 3;
        in = (bank < 2) ? (Ws2 + (size_t)bank * HD) : (Wg2 + (size_t)(bank - 2) * HD);
        out = W2t + (size_t)bank * HD;
    }
    const int r0 = (tile_i >> cshift) * 64;
    const int c0 = (tile_i & ((1 << cshift) - 1)) * 64;
    const int R = (C == Hm) ? Dm : Hm;
    const int t = threadIdx.x;
    {
        int r = t >> 2, cs = (t & 3) * 16;
        const float4* src = (const float4*)(in + (size_t)(r0 + r) * C + c0 + cs);
        #pragma unroll
        for (int i = 0; i < 4; i++) {
            float4 v = src[i];
            tile[r][cs + i * 4 + 0] = v.x;
            tile[r][cs + i * 4 + 1] = v.y;
            tile[r][cs + i * 4 + 2] = v.z;
            tile[r][cs + i * 4 + 3] = v.w;
        }
    }
    __syncthreads();
    {
        int c = t >> 2, rs = (t & 3) * 16;
        __bf16* dst = out + (size_t)(c0 + c) * R + r0 + rs;
        bf16x8 v0, v1;
        #pragma unroll
        for (int i = 0; i < 8; i++) v0[i] = (__bf16)tile[rs + i][c];
        #pragma unroll
        for (int i = 0; i < 8; i++) v1[i] = (__bf16)tile[rs + 8 + i][c];
        *(bf16x8*)dst = v0;
        *(bf16x8*)(dst + 8) = v1;
    }
}

// ---------------------------------------------------------------- FFN GEMM 1
// barrier-free streaming: A/B fragments loaded directly from global (b128 per
// lane, immediate offsets), compiler software-pipelines with vmcnt(N).
// block = 128m x 64n, 4 waves of 64m x 32n; grid = MAXMT*16
__global__ __launch_bounds__(256) void k_ffn1s(
    const __bf16* __restrict__ xb, const __bf16* __restrict__ W1t,
    const float* __restrict__ bs1, const float* __restrict__ bg1,
    const int* __restrict__ counts, const int* __restrict__ lists,
    const int2* __restrict__ table, const int* __restrict__ ntot,
    __bf16* __restrict__ hb)
{
    const int mt = blockIdx.x >> 4;
    if (mt >= *ntot) return;
    const int nt = blockIdx.x & 15;
    const int2 te = table[mt];
    const int bank = te.x, m0 = te.y;
    const int cnt = (bank < 2) ? NTOK : counts[(bank - 2) >> 1];
    const int n0 = nt * 64;

    __shared__ int tok_lds[128];
    const int t = threadIdx.x;
    if (t < 128) {
        int idx = m0 + t;
        int tok = -1;
        if (idx < cnt) tok = (bank < 2) ? idx : lists[((bank - 2) >> 1) * NTOK + idx];
        tok_lds[t] = tok;
    }
    __syncthreads();

    const int wave = t >> 6, lane = t & 63;
    const int col = lane & 15, quad = lane >> 4;
    const int mh = (wave >> 1) * 64, nh = (wave & 1) * 32;

    const __bf16* ap[4];
    #pragma unroll
    for (int mf = 0; mf < 4; mf++) {
        int tok = tok_lds[mh + mf * 16 + col];
        ap[mf] = xb + (size_t)(tok < 0 ? 0 : tok) * Dm + quad * 8;
    }
    const __bf16* wb = W1t + (size_t)bank * Hm * Dm;
    const __bf16* bp[2];
    #pragma unroll
    for (int nf = 0; nf < 2; nf++)
        bp[nf] = wb + (size_t)(n0 + nh + nf * 16 + col) * Dm + quad * 8;

    floatx4 acc[4][2] = {};

    #pragma unroll 4
    for (int kk = 0; kk < Dm / 32; kk++) {
        bf16x8 af[4], bfv[2];
        #pragma unroll
        for (int mf = 0; mf < 4; mf++) af[mf] = *(const bf16x8*)(ap[mf] + kk * 32);
        #pragma unroll
        for (int nf = 0; nf < 2; nf++) bfv[nf] = *(const bf16x8*)(bp[nf] + kk * 32);
        #pragma unroll
        for (int mf = 0; mf < 4; mf++)
            #pragma unroll
            for (int nf = 0; nf < 2; nf++)
                acc[mf][nf] = __builtin_amdgcn_mfma_f32_16x16x32_bf16(af[mf], bfv[nf], acc[mf][nf], 0, 0, 0);
    }

    const int e = (bank < 2) ? bank : 2 + ((bank - 2) & 1);
    const float* b1p = (bank < 2) ? (bs1 + bank * Hm) : (bg1 + (size_t)(bank - 2) * Hm);
    float bias[2];
    #pragma unroll
    for (int nf = 0; nf < 2; nf++) bias[nf] = b1p[n0 + nh + nf * 16 + col];

    #pragma unroll
    for (int mf = 0; mf < 4; mf++) {
        #pragma unroll
        for (int r = 0; r < 4; r++) {
            int m = mh + mf * 16 + quad * 4 + r;
            int tok = tok_lds[m];
            if (tok >= 0) {
                __bf16* hrow = hb + ((size_t)tok * Em + e) * Hm + n0 + nh + col;
                #pragma unroll
                for (int nf = 0; nf < 2; nf++)
                    hrow[nf * 16] = (__bf16)fmaxf(acc[mf][nf][r] + bias[nf], 0.0f);
            }
        }
    }
}

// ---------------------------------------------------------------- FFN GEMM 2
// same structure, K=1024, fp32 out; grid = MAXMT*8
__global__ __launch_bounds__(256) void k_ffn2s(
    const __bf16* __restrict__ hb, const __bf16* __restrict__ W2t,
    const float* __restrict__ bs2, const float* __restrict__ bg2,
    const int* __restrict__ counts, const int* __restrict__ lists,
    const int2* __restrict__ table, const int* __restrict__ ntot,
    float* __restrict__ eo)
{
    const int mt = blockIdx.x >> 3;
    if (mt >= *ntot) return;
    const int nt = blockIdx.x & 7;
    const int2 te = table[mt];
    const int bank = te.x, m0 = te.y;
    const int cnt = (bank < 2) ? NTOK : counts[(bank - 2) >> 1];
    const int n0 = nt * 64;
    const int e = (bank < 2) ? bank : 2 + ((bank - 2) & 1);

    __shared__ int tok_lds[128];
    const int t = threadIdx.x;
    if (t < 128) {
        int idx = m0 + t;
        int tok = -1;
        if (idx < cnt) tok = (bank < 2) ? idx : lists[((bank - 2) >> 1) * NTOK + idx];
        tok_lds[t] = tok;
    }
    __syncthreads();

    const int wave = t >> 6, lane = t & 63;
    const int col = lane & 15, quad = lane >> 4;
    const int mh = (wave >> 1) * 64, nh = (wave & 1) * 32;

    const __bf16* ap[4];
    #pragma unroll
    for (int mf = 0; mf < 4; mf++) {
        int tok = tok_lds[mh + mf * 16 + col];
        ap[mf] = hb + ((size_t)(tok < 0 ? 0 : tok) * Em + e) * Hm + quad * 8;
    }
    const __bf16* wb = W2t + (size_t)bank * Hm * Dm;
    const __bf16* bp[2];
    #pragma unroll
    for (int nf = 0; nf < 2; nf++)
        bp[nf] = wb + (size_t)(n0 + nh + nf * 16 + col) * Hm + quad * 8;

    floatx4 acc[4][2] = {};

    #pragma unroll 4
    for (int kk = 0; kk < Hm / 32; kk++) {
        bf16x8 af[4], bfv[2];
        #pragma unroll
        for (int mf = 0; mf < 4; mf++) af[mf] = *(const bf16x8*)(ap[mf] + kk * 32);
        #pragma unroll
        for (int nf = 0; nf < 2; nf++) bfv[nf] = *(const bf16x8*)(bp[nf] + kk * 32);
        #pragma unroll
        for (int mf = 0; mf < 4; mf++)
            #pragma unroll
            for (int nf = 0; nf < 2; nf++)
                acc[mf][nf] = __builtin_amdgcn_mfma_f32_16x16x32_bf16(af[mf], bfv[nf], acc[mf][nf], 0, 0, 0);
    }

    const float* b2p = (bank < 2) ? (bs2 + bank * Dm) : (bg2 + (size_t)(bank - 2) * Dm);
    float bias[2];
    #pragma unroll
    for (int nf = 0; nf < 2; nf++) bias[nf] = b2p[n0 + nh + nf * 16 + col];

    #pragma unroll
    for (int mf = 0; mf < 4; mf++) {
        #pragma unroll
        for (int r = 0; r < 4; r++) {
            int m = mh + mf * 16 + quad * 4 + r;
            int tok = tok_lds[m];
            if (tok >= 0) {
                float* erow = eo + ((size_t)tok * Em + e) * Dm + n0 + nh + col;
                #pragma unroll
                for (int nf = 0; nf < 2; nf++)
                    erow[nf * 16] = acc[mf][nf][r] + bias[nf];
            }
        }
    }
}

// ---------------------------------------------------------------- gate
// gate_W cached in LDS (stride 13 -> 2-way-free bank pattern); wave-per-token,
// lane covers features f = lane + 64*j; butterfly reduce; 16 tokens/block.
__global__ __launch_bounds__(256) void k_gate(
    const float* __restrict__ x, const float* __restrict__ cond_emb,
    const int* __restrict__ gids, const float* __restrict__ gW,
    const float* __restrict__ gb, float* __restrict__ wts)
{
    __shared__ float gwl[544 * 13];
    const int t = threadIdx.x;
    for (int i = t; i < 544 * 12; i += 256) {
        int f = i / 12, j = i - f * 12;
        gwl[f * 13 + j] = gW[((size_t)(j >> 2) * 544 + f) * 4 + (j & 3)];
    }
    __syncthreads();

    const int wave = t >> 6, lane = t & 63;
    #pragma unroll
    for (int it = 0; it < 4; it++) {
        const int n = blockIdx.x * 16 + wave * 4 + it;
        const int gid = gids[n];
        const float* xr = x + (size_t)n * Dm;
        float a[12] = {};
        #pragma unroll
        for (int j = 0; j < 8; j++) {
            float xv = xr[j * 64 + lane];
            const float* base = &gwl[(j * 64 + lane) * 13];
            #pragma unroll
            for (int jj = 0; jj < 12; jj++) a[jj] += xv * base[jj];
        }
        if (lane < Cm) {
            float xv = cond_emb[gid * Cm + lane];
            const float* base = &gwl[(Dm + lane) * 13];
            #pragma unroll
            for (int jj = 0; jj < 12; jj++) a[jj] += xv * base[jj];
        }
        #pragma unroll
        for (int off = 1; off < 64; off <<= 1)
            #pragma unroll
            for (int jj = 0; jj < 12; jj++)
                a[jj] += __shfl_xor(a[jj], off, 64);

        if (lane < Km) {
            int k = lane;
            float v0 = a[k * 4 + 0] + gb[k * 4 + 0];
            float v1 = a[k * 4 + 1] + gb[k * 4 + 1];
            float v2 = a[k * 4 + 2] + gb[k * 4 + 2];
            float v3 = a[k * 4 + 3] + gb[k * 4 + 3];
            float m = fmaxf(fmaxf(v0, v1), fmaxf(v2, v3));
            float e0 = __expf(v0 - m), e1 = __expf(v1 - m), e2 = __expf(v2 - m), e3 = __expf(v3 - m);
            float inv = 1.0f / (e0 + e1 + e2 + e3);
            *(float4*)(wts + (size_t)n * 12 + k * 4) =
                make_float4(e0 * inv, e1 * inv, e2 * inv, e3 * inv);
        }
    }
}

// ---------------------------------------------------------------- combine
__global__ __launch_bounds__(256) void k_combine(
    const float* __restrict__ eo, const float* __restrict__ wts,
    float* __restrict__ out)
{
    const int t = threadIdx.x;
    const int tok = blockIdx.x * 4 + (t >> 6);
    const int d0 = (t & 63) * 8;
    const float* ep = eo + (size_t)tok * Em * Dm;

    float w[Km][Em];
    #pragma unroll
    for (int k = 0; k < Km; k++)
        #pragma unroll
        for (int e = 0; e < Em; e++)
            w[k][e] = wts[(size_t)tok * 12 + k * 4 + e];

    float4 o0[Km], o1[Km];
    #pragma unroll
    for (int k = 0; k < Km; k++) { o0[k] = make_float4(0, 0, 0, 0); o1[k] = make_float4(0, 0, 0, 0); }

    #pragma unroll
    for (int e = 0; e < Em; e++) {
        float4 a = *(const float4*)(ep + (size_t)e * Dm + d0);
        float4 b = *(const float4*)(ep + (size_t)e * Dm + d0 + 4);
        #pragma unroll
        for (int k = 0; k < Km; k++) {
            float wk = w[k][e];
            o0[k].x += wk * a.x; o0[k].y += wk * a.y; o0[k].z += wk * a.z; o0[k].w += wk * a.w;
            o1[k].x += wk * b.x; o1[k].y += wk * b.y; o1[k].z += wk * b.z; o1[k].w += wk * b.w;
        }
    }
    #pragma unroll
    for (int k = 0; k < Km; k++) {
        float* op = out + ((size_t)k * NTOK + tok) * Dm + d0;
        *(float4*)op = o0[k];
        *(float4*)(op + 4) = o1[k];
    }
}

// ---------------------------------------------------------------- launch

static inline size_t align256(size_t v) { return (v + 255) & ~(size_t)255; }

extern "C" void kernel_launch(void* const* d_in, const int* in_sizes, int n_in,
                              void* d_out, int out_size, void* d_ws, size_t ws_size,
                              hipStream_t stream) {
    const float* x        = (const float*)d_in[0];
    const int*   ids      = (const int*)d_in[1];
    const int*   e2g      = (const int*)d_in[2];
    const float* Ws1      = (const float*)d_in[3];
    const float* bs1      = (const float*)d_in[4];
    const float* Ws2      = (const float*)d_in[5];
    const float* bs2      = (const float*)d_in[6];
    const float* Wg1      = (const float*)d_in[7];
    const float* bg1      = (const float*)d_in[8];
    const float* Wg2      = (const float*)d_in[9];
    const float* bg2      = (const float*)d_in[10];
    const float* cond_emb = (const float*)d_in[11];
    const float* gate_W   = (const float*)d_in[12];
    const float* gate_b   = (const float*)d_in[13];
    float* out = (float*)d_out;

    char* ws = (char*)d_ws;
    size_t off = 0;
    const size_t HD = (size_t)Hm * Dm;

    __bf16* xb  = (__bf16*)(ws + off); off = align256(off + (size_t)NTOK * Dm * 2);
    __bf16* W1t = (__bf16*)(ws + off); off = align256(off + (size_t)NBANK * HD * 2);
    __bf16* W2t = (__bf16*)(ws + off); off = align256(off + (size_t)NBANK * HD * 2);
    __bf16* hb  = (__bf16*)(ws + off); off = align256(off + (size_t)NTOK * Em * Hm * 2);
    float*  eo  = (float*)(ws + off);  off = align256(off + (size_t)NTOK * Em * Dm * 4);
    int*    gids   = (int*)(ws + off); off = align256(off + (size_t)NTOK * 4);
    int*    counts = (int*)(ws + off); off = align256(off + 256);
    int*    lists  = (int*)(ws + off); off = align256(off + (size_t)NGm * NTOK * 4);
    float*  wts    = (float*)(ws + off); off = align256(off + (size_t)NTOK * 12 * 4);
    int2*   table  = (int2*)(ws + off); off = align256(off + (size_t)MAXMT * 8);
    int*    ntot   = (int*)(ws + off);  off = align256(off + 256);
    (void)ws_size; (void)n_in; (void)in_sizes; (void)out_size;

    // 1) bucket + tile plan (single block)
    k_prep<<<1, 1024, 0, stream>>>(ids, e2g, gids, counts, lists, table, ntot);

    // 2) conversions (x -> bf16; all 4 weight transposes in one dispatch)
    k_cvt<<<(NTOK * Dm) / (8 * 256), 256, 0, stream>>>(x, xb, NTOK * Dm);
    k_trans_all<<<3584, 256, 0, stream>>>(Ws1, Wg1, Ws2, Wg2, W1t, W2t);

    // 3) FFN layer 1 (barrier-free streaming GEMM, relu, bf16 out)
    k_ffn1s<<<MAXMT * 16, 256, 0, stream>>>(xb, W1t, bs1, bg1, counts, lists, table, ntot, hb);

    // 4) FFN layer 2 (fp32 out)
    k_ffn2s<<<MAXMT * 8, 256, 0, stream>>>(hb, W2t, bs2, bg2, counts, lists, table, ntot, eo);

    // 5) gates
    k_gate<<<NTOK / 16, 256, 0, stream>>>(x, cond_emb, gids, gate_W, gate_b, wts);

    // 6) combine
    k_combine<<<NTOK / 4, 256, 0, stream>>>(eo, wts, out);
}

// Round 4
// 257.837 us; speedup vs baseline: 1.4805x; 1.4805x over previous
//
#include <hip/hip_runtime.h>
#include <hip/hip_bf16.h>
#include <cmath>

// Problem constants (from reference)
#define NTOK 4096      // B*T
#define Dm   512
#define Hm   1024
#define Cm   32
#define Km   3
#define NEVm 50
#define NGm  6
#define NBANK 14       // 2 shared + 12 group banks
#define Em   4         // S+G
#define MAXMT 144      // worst-case 128-token m-tiles: 64 shared + <=80 group

typedef __bf16 bf16x8 __attribute__((ext_vector_type(8)));
typedef float  floatx4 __attribute__((ext_vector_type(4)));

// async global->LDS 16B: per-lane global addr, wave-uniform LDS base + lane*16
__device__ __forceinline__ void async16(const __bf16* g, const __bf16* l) {
    __builtin_amdgcn_global_load_lds(
        (const __attribute__((address_space(1))) void*)g,
        (__attribute__((address_space(3))) void*)l, 16, 0, 0);
}

// ---------------------------------------------------------------- prep
__global__ __launch_bounds__(1024) void k_prep(
    const int* __restrict__ ids, const int* __restrict__ e2g,
    int* __restrict__ gids, int* __restrict__ counts,
    int* __restrict__ lists, int2* __restrict__ table, int* __restrict__ ntot)
{
    __shared__ int lcnt[NGm];
    const int t = threadIdx.x;
    const int lane = t & 63;
    if (t < NGm) lcnt[t] = 0;
    __syncthreads();
    for (int n = t; n < NTOK; n += 1024) {
        int id = ids[n];
        id = id < 0 ? 0 : (id > NEVm - 1 ? NEVm - 1 : id);
        int g = e2g[id];
        gids[n] = g;
        int pos = 0;
        #pragma unroll
        for (int gg = 0; gg < NGm; gg++) {
            unsigned long long m = __ballot(g == gg);
            if (g == gg) {
                int leader = __ffsll((unsigned long long)m) - 1;
                int base = 0;
                if (lane == leader) base = atomicAdd(&lcnt[gg], (int)__popcll(m));
                base = __shfl(base, leader, 64);
                pos = base + (int)__popcll(m & ((1ull << lane) - 1));
            }
        }
        lists[g * NTOK + pos] = n;
    }
    __syncthreads();
    if (t < NGm) counts[t] = lcnt[t];
    if (t == 0) {
        int idx = 0;
        for (int b = 0; b < 2; b++)
            for (int m0 = 0; m0 < NTOK; m0 += 128) table[idx++] = make_int2(b, m0);
        for (int g = 0; g < NGm; g++) {
            int c = lcnt[g];
            for (int gg = 0; gg < 2; gg++) {
                int bank = 2 + 2 * g + gg;
                for (int m0 = 0; m0 < c; m0 += 128) table[idx++] = make_int2(bank, m0);
            }
        }
        *ntot = idx;
    }
}

// fp32 -> bf16 elementwise
__global__ void k_cvt(const float* __restrict__ in, __bf16* __restrict__ out, int n) {
    int i = (blockIdx.x * 256 + threadIdx.x) * 8;
    if (i >= n) return;
    float4 a = *(const float4*)(in + i);
    float4 b = *(const float4*)(in + i + 4);
    bf16x8 v;
    v[0] = (__bf16)a.x; v[1] = (__bf16)a.y; v[2] = (__bf16)a.z; v[3] = (__bf16)a.w;
    v[4] = (__bf16)b.x; v[5] = (__bf16)b.y; v[6] = (__bf16)b.z; v[7] = (__bf16)b.w;
    *(bf16x8*)(out + i) = v;
}

// all four weight transposes in ONE dispatch (fp32 [R][C] -> bf16 [C][R])
__global__ __launch_bounds__(256) void k_trans_all(
    const float* __restrict__ Ws1, const float* __restrict__ Wg1,
    const float* __restrict__ Ws2, const float* __restrict__ Wg2,
    __bf16* __restrict__ W1t, __bf16* __restrict__ W2t)
{
    __shared__ float tile[64][65];
    int idx = blockIdx.x;
    const float* in; __bf16* out; int C, cshift, tile_i;
    const size_t HD = (size_t)Hm * Dm;
    if (idx < 1792) {
        int bank = idx >> 7; tile_i = idx & 127;
        C = Hm; cshift = 4;
        in = (bank < 2) ? (Ws1 + (size_t)bank * HD) : (Wg1 + (size_t)(bank - 2) * HD);
        out = W1t + (size_t)bank * HD;
    } else {
        idx -= 1792;
        int bank = idx >> 7; tile_i = idx & 127;
        C = Dm; cshift = 3;
        in = (bank < 2) ? (Ws2 + (size_t)bank * HD) : (Wg2 + (size_t)(bank - 2) * HD);
        out = W2t + (size_t)bank * HD;
    }
    const int r0 = (tile_i >> cshift) * 64;
    const int c0 = (tile_i & ((1 << cshift) - 1)) * 64;
    const int R = (C == Hm) ? Dm : Hm;
    const int t = threadIdx.x;
    {
        int r = t >> 2, cs = (t & 3) * 16;
        const float4* src = (const float4*)(in + (size_t)(r0 + r) * C + c0 + cs);
        #pragma unroll
        for (int i = 0; i < 4; i++) {
            float4 v = src[i];
            tile[r][cs + i * 4 + 0] = v.x;
            tile[r][cs + i * 4 + 1] = v.y;
            tile[r][cs + i * 4 + 2] = v.z;
            tile[r][cs + i * 4 + 3] = v.w;
        }
    }
    __syncthreads();
    {
        int c = t >> 2, rs = (t & 3) * 16;
        __bf16* dst = out + (size_t)(c0 + c) * R + r0 + rs;
        bf16x8 v0, v1;
        #pragma unroll
        for (int i = 0; i < 8; i++) v0[i] = (__bf16)tile[rs + i][c];
        #pragma unroll
        for (int i = 0; i < 8; i++) v1[i] = (__bf16)tile[rs + 8 + i][c];
        *(bf16x8*)dst = v0;
        *(bf16x8*)(dst + 8) = v1;
    }
}

// ---------------------------------------------------------------- fused FFN GEMM
// 128x128 tile, BK=64, double-buffered LDS with prefetch-across-barrier.
// XOR-swizzled 16B granules (applied on global side of the LDS-DMA) so
// fragment ds_read_b128 is 2-way-conflict-free at LDS row stride 128B.
// A rows gathered by token; O rows scattered by token. bf16 out.
template<int KDIM, int NDIM, bool RELU>
__global__ __launch_bounds__(256) void k_ffn(
    const __bf16* __restrict__ Abase, int AstrTok, int AeStr,
    const __bf16* __restrict__ Wt,
    const float* __restrict__ bsh, const float* __restrict__ bgr,
    const int* __restrict__ counts, const int* __restrict__ lists,
    const int2* __restrict__ table, const int* __restrict__ ntot,
    __bf16* __restrict__ Obase, int OstrTok, int OeStr)
{
    constexpr int NT = NDIM / 128;   // n-tiles
    constexpr int KT = KDIM / 64;    // k-tiles
    const int mt = blockIdx.x / NT;
    if (mt >= *ntot) return;
    const int nt = blockIdx.x % NT;
    const int2 te = table[mt];
    const int bank = te.x, m0 = te.y;
    const int cnt = (bank < 2) ? NTOK : counts[(bank - 2) >> 1];
    const int n0 = nt * 128;
    const int e = (bank < 2) ? bank : 2 + ((bank - 2) & 1);

    __shared__ int tok_lds[128];
    __shared__ __align__(16) __bf16 A_lds[2][128 * 64];
    __shared__ __align__(16) __bf16 B_lds[2][128 * 64];

    const int t = threadIdx.x;
    if (t < 128) {
        int idx = m0 + t;
        int tok = -1;
        if (idx < cnt) tok = (bank < 2) ? idx : lists[((bank - 2) >> 1) * NTOK + idx];
        tok_lds[t] = tok;
    }
    __syncthreads();

    const int w = t >> 6, lane = t & 63;
    const int jr = lane >> 3, sg = lane & 7;

    // per-thread global base pointers for the 8 staging instructions
    const __bf16* aGB[4]; const __bf16* bGB[4];
    #pragma unroll
    for (int j = 0; j < 4; j++) {
        int r = (w * 4 + j) * 8 + jr;
        int gg = sg ^ (r & 7);
        int tok = tok_lds[r]; if (tok < 0) tok = 0;
        aGB[j] = Abase + (size_t)tok * AstrTok + (size_t)e * AeStr + gg * 8;
        bGB[j] = Wt + (size_t)bank * NDIM * KDIM + (size_t)(n0 + r) * KDIM + gg * 8;
    }

    // fragment LDS element offsets (row-major stride 64 elems; swizzled granule)
    const int col = lane & 15, quad = lane >> 4;
    const int mh = (w >> 1) * 64, nh = (w & 1) * 64;
    const int swz = col & 7;
    int aoff[2][4], boff[2][4];
    #pragma unroll
    for (int ks = 0; ks < 2; ks++)
        #pragma unroll
        for (int f = 0; f < 4; f++) {
            int gk = ((ks * 4 + quad) ^ swz) * 8;
            aoff[ks][f] = (mh + f * 16 + col) * 64 + gk;
            boff[ks][f] = (nh + f * 16 + col) * 64 + gk;
        }

    floatx4 acc[4][4] = {};

    // prologue: stage tile 0
    #pragma unroll
    for (int j = 0; j < 4; j++) async16(aGB[j], &A_lds[0][(w * 4 + j) * 512]);
    #pragma unroll
    for (int j = 0; j < 4; j++) async16(bGB[j], &B_lds[0][(w * 4 + j) * 512]);
    __syncthreads();

    #pragma unroll 2
    for (int kt = 0; kt < KT; kt++) {
        const int p = kt & 1, q = p ^ 1;
        if (kt + 1 < KT) {  // prefetch next tile; flies during MFMA below
            const int ko = (kt + 1) * 64;
            #pragma unroll
            for (int j = 0; j < 4; j++) async16(aGB[j] + ko, &A_lds[q][(w * 4 + j) * 512]);
            #pragma unroll
            for (int j = 0; j < 4; j++) async16(bGB[j] + ko, &B_lds[q][(w * 4 + j) * 512]);
        }
        bf16x8 af[2][4], bv[2][4];
        #pragma unroll
        for (int ks = 0; ks < 2; ks++)
            #pragma unroll
            for (int f = 0; f < 4; f++) {
                af[ks][f] = *(const bf16x8*)&A_lds[p][aoff[ks][f]];
                bv[ks][f] = *(const bf16x8*)&B_lds[p][boff[ks][f]];
            }
        #pragma unroll
        for (int ks = 0; ks < 2; ks++)
            #pragma unroll
            for (int mf = 0; mf < 4; mf++)
                #pragma unroll
                for (int nf = 0; nf < 4; nf++)
                    acc[mf][nf] = __builtin_amdgcn_mfma_f32_16x16x32_bf16(
                        af[ks][mf], bv[ks][nf], acc[mf][nf], 0, 0, 0);
        __syncthreads();
    }

    const float* bp = (bank < 2) ? (bsh + (size_t)bank * NDIM)
                                 : (bgr + (size_t)(bank - 2) * NDIM);
    float bias[4];
    #pragma unroll
    for (int nf = 0; nf < 4; nf++) bias[nf] = bp[n0 + nh + nf * 16 + col];

    #pragma unroll
    for (int mf = 0; mf < 4; mf++) {
        #pragma unroll
        for (int r = 0; r < 4; r++) {
            int m = mh + mf * 16 + quad * 4 + r;
            int tok = tok_lds[m];
            if (tok >= 0) {
                __bf16* orow = Obase + (size_t)tok * OstrTok + (size_t)e * OeStr + n0 + nh + col;
                #pragma unroll
                for (int nf = 0; nf < 4; nf++) {
                    float v = acc[mf][nf][r] + bias[nf];
                    if (RELU) v = fmaxf(v, 0.0f);
                    orow[nf * 16] = (__bf16)v;
                }
            }
        }
    }
}

// ---------------------------------------------------------------- gate
__global__ __launch_bounds__(256) void k_gate(
    const float* __restrict__ x, const float* __restrict__ cond_emb,
    const int* __restrict__ gids, const float* __restrict__ gW,
    const float* __restrict__ gb, float* __restrict__ wts)
{
    __shared__ float gwl[544 * 13];
    const int t = threadIdx.x;
    for (int i = t; i < 544 * 12; i += 256) {
        int f = i / 12, j = i - f * 12;
        gwl[f * 13 + j] = gW[((size_t)(j >> 2) * 544 + f) * 4 + (j & 3)];
    }
    __syncthreads();

    const int wave = t >> 6, lane = t & 63;
    #pragma unroll
    for (int it = 0; it < 4; it++) {
        const int n = blockIdx.x * 16 + wave * 4 + it;
        const int gid = gids[n];
        const float* xr = x + (size_t)n * Dm;
        float a[12] = {};
        #pragma unroll
        for (int j = 0; j < 8; j++) {
            float xv = xr[j * 64 + lane];
            const float* base = &gwl[(j * 64 + lane) * 13];
            #pragma unroll
            for (int jj = 0; jj < 12; jj++) a[jj] += xv * base[jj];
        }
        if (lane < Cm) {
            float xv = cond_emb[gid * Cm + lane];
            const float* base = &gwl[(Dm + lane) * 13];
            #pragma unroll
            for (int jj = 0; jj < 12; jj++) a[jj] += xv * base[jj];
        }
        #pragma unroll
        for (int off = 1; off < 64; off <<= 1)
            #pragma unroll
            for (int jj = 0; jj < 12; jj++)
                a[jj] += __shfl_xor(a[jj], off, 64);

        if (lane < Km) {
            int k = lane;
            float v0 = a[k * 4 + 0] + gb[k * 4 + 0];
            float v1 = a[k * 4 + 1] + gb[k * 4 + 1];
            float v2 = a[k * 4 + 2] + gb[k * 4 + 2];
            float v3 = a[k * 4 + 3] + gb[k * 4 + 3];
            float m = fmaxf(fmaxf(v0, v1), fmaxf(v2, v3));
            float e0 = __expf(v0 - m), e1 = __expf(v1 - m), e2 = __expf(v2 - m), e3 = __expf(v3 - m);
            float inv = 1.0f / (e0 + e1 + e2 + e3);
            *(float4*)(wts + (size_t)n * 12 + k * 4) =
                make_float4(e0 * inv, e1 * inv, e2 * inv, e3 * inv);
        }
    }
}

// ---------------------------------------------------------------- combine
// out[k][tok][d] = sum_e wts[tok][k][e] * eo[tok][e][d]   (eo is bf16)
__global__ __launch_bounds__(256) void k_combine(
    const __bf16* __restrict__ eo, const float* __restrict__ wts,
    float* __restrict__ out)
{
    const int t = threadIdx.x;
    const int tok = blockIdx.x * 4 + (t >> 6);
    const int d0 = (t & 63) * 8;
    const __bf16* ep = eo + (size_t)tok * Em * Dm;

    float w[Km][Em];
    #pragma unroll
    for (int k = 0; k < Km; k++)
        #pragma unroll
        for (int e = 0; e < Em; e++)
            w[k][e] = wts[(size_t)tok * 12 + k * 4 + e];

    float o[Km][8] = {};
    #pragma unroll
    for (int e = 0; e < Em; e++) {
        bf16x8 v = *(const bf16x8*)(ep + (size_t)e * Dm + d0);
        float f[8];
        #pragma unroll
        for (int i = 0; i < 8; i++) f[i] = (float)v[i];
        #pragma unroll
        for (int k = 0; k < Km; k++)
            #pragma unroll
            for (int i = 0; i < 8; i++) o[k][i] += w[k][e] * f[i];
    }
    #pragma unroll
    for (int k = 0; k < Km; k++) {
        float* op = out + ((size_t)k * NTOK + tok) * Dm + d0;
        float4 a = make_float4(o[k][0], o[k][1], o[k][2], o[k][3]);
        float4 b = make_float4(o[k][4], o[k][5], o[k][6], o[k][7]);
        *(float4*)op = a;
        *(float4*)(op + 4) = b;
    }
}

// ---------------------------------------------------------------- launch

static inline size_t align256(size_t v) { return (v + 255) & ~(size_t)255; }

extern "C" void kernel_launch(void* const* d_in, const int* in_sizes, int n_in,
                              void* d_out, int out_size, void* d_ws, size_t ws_size,
                              hipStream_t stream) {
    const float* x        = (const float*)d_in[0];
    const int*   ids      = (const int*)d_in[1];
    const int*   e2g      = (const int*)d_in[2];
    const float* Ws1      = (const float*)d_in[3];
    const float* bs1      = (const float*)d_in[4];
    const float* Ws2      = (const float*)d_in[5];
    const float* bs2      = (const float*)d_in[6];
    const float* Wg1      = (const float*)d_in[7];
    const float* bg1      = (const float*)d_in[8];
    const float* Wg2      = (const float*)d_in[9];
    const float* bg2      = (const float*)d_in[10];
    const float* cond_emb = (const float*)d_in[11];
    const float* gate_W   = (const float*)d_in[12];
    const float* gate_b   = (const float*)d_in[13];
    float* out = (float*)d_out;

    char* ws = (char*)d_ws;
    size_t off = 0;
    const size_t HD = (size_t)Hm * Dm;

    __bf16* xb  = (__bf16*)(ws + off); off = align256(off + (size_t)NTOK * Dm * 2);
    __bf16* W1t = (__bf16*)(ws + off); off = align256(off + (size_t)NBANK * HD * 2);
    __bf16* W2t = (__bf16*)(ws + off); off = align256(off + (size_t)NBANK * HD * 2);
    __bf16* hb  = (__bf16*)(ws + off); off = align256(off + (size_t)NTOK * Em * Hm * 2);
    __bf16* eo  = (__bf16*)(ws + off); off = align256(off + (size_t)NTOK * Em * Dm * 2);
    int*    gids   = (int*)(ws + off); off = align256(off + (size_t)NTOK * 4);
    int*    counts = (int*)(ws + off); off = align256(off + 256);
    int*    lists  = (int*)(ws + off); off = align256(off + (size_t)NGm * NTOK * 4);
    float*  wts    = (float*)(ws + off); off = align256(off + (size_t)NTOK * 12 * 4);
    int2*   table  = (int2*)(ws + off); off = align256(off + (size_t)MAXMT * 8);
    int*    ntot   = (int*)(ws + off);  off = align256(off + 256);
    (void)ws_size; (void)n_in; (void)in_sizes; (void)out_size;

    // 1) bucket + tile plan
    k_prep<<<1, 1024, 0, stream>>>(ids, e2g, gids, counts, lists, table, ntot);

    // 2) conversions
    k_cvt<<<(NTOK * Dm) / (8 * 256), 256, 0, stream>>>(x, xb, NTOK * Dm);
    k_trans_all<<<3584, 256, 0, stream>>>(Ws1, Wg1, Ws2, Wg2, W1t, W2t);

    // 3) FFN layer 1: x[tok] @ W1t[bank] -> relu -> hb[tok][e][:]
    k_ffn<Dm, Hm, true><<<MAXMT * (Hm / 128), 256, 0, stream>>>(
        xb, Dm, 0, W1t, bs1, bg1, counts, lists, table, ntot,
        hb, Em * Hm, Hm);

    // 4) FFN layer 2: hb[tok][e] @ W2t[bank] -> eo[tok][e][:] (bf16)
    k_ffn<Hm, Dm, false><<<MAXMT * (Dm / 128), 256, 0, stream>>>(
        hb, Em * Hm, Hm, W2t, bs2, bg2, counts, lists, table, ntot,
        eo, Em * Dm, Dm);

    // 5) gates
    k_gate<<<NTOK / 16, 256, 0, stream>>>(x, cond_emb, gids, gate_W, gate_b, wts);

    // 6) combine
    k_combine<<<NTOK / 4, 256, 0, stream>>>(eo, wts, out);
}

// Round 5
// 239.377 us; speedup vs baseline: 1.5946x; 1.0771x over previous
//
#include <hip/hip_runtime.h>
#include <hip/hip_bf16.h>
#include <cmath>

// Problem constants (from reference)
#define NTOK 4096      // B*T
#define Dm   512
#define Hm   1024
#define Cm   32
#define Km   3
#define NEVm 50
#define NGm  6
#define NBANK 14       // 2 shared + 12 group banks
#define Em   4         // S+G
#define MAXMT 144      // worst-case 128-token m-tiles

typedef __bf16 bf16x8 __attribute__((ext_vector_type(8)));
typedef float  floatx4 __attribute__((ext_vector_type(4)));

__device__ __forceinline__ void async16(const __bf16* g, const __bf16* l) {
    __builtin_amdgcn_global_load_lds(
        (const __attribute__((address_space(1))) void*)g,
        (__attribute__((address_space(3))) void*)l, 16, 0, 0);
}

// ---------------------------------------------------------------- prep
__global__ __launch_bounds__(1024) void k_prep(
    const int* __restrict__ ids, const int* __restrict__ e2g,
    int* __restrict__ gids, int* __restrict__ counts,
    int* __restrict__ lists, int2* __restrict__ table, int* __restrict__ ntot)
{
    __shared__ int lcnt[NGm];
    const int t = threadIdx.x;
    const int lane = t & 63;
    if (t < NGm) lcnt[t] = 0;
    __syncthreads();
    for (int n = t; n < NTOK; n += 1024) {
        int id = ids[n];
        id = id < 0 ? 0 : (id > NEVm - 1 ? NEVm - 1 : id);
        int g = e2g[id];
        gids[n] = g;
        int pos = 0;
        #pragma unroll
        for (int gg = 0; gg < NGm; gg++) {
            unsigned long long m = __ballot(g == gg);
            if (g == gg) {
                int leader = __ffsll((unsigned long long)m) - 1;
                int base = 0;
                if (lane == leader) base = atomicAdd(&lcnt[gg], (int)__popcll(m));
                base = __shfl(base, leader, 64);
                pos = base + (int)__popcll(m & ((1ull << lane) - 1));
            }
        }
        lists[g * NTOK + pos] = n;
    }
    __syncthreads();
    if (t < NGm) counts[t] = lcnt[t];
    if (t == 0) {
        int idx = 0;
        for (int b = 0; b < 2; b++)
            for (int m0 = 0; m0 < NTOK; m0 += 128) table[idx++] = make_int2(b, m0);
        for (int g = 0; g < NGm; g++) {
            int c = lcnt[g];
            for (int gg = 0; gg < 2; gg++) {
                int bank = 2 + 2 * g + gg;
                for (int m0 = 0; m0 < c; m0 += 128) table[idx++] = make_int2(bank, m0);
            }
        }
        *ntot = idx;
    }
}

// fp32 -> bf16 elementwise
__global__ void k_cvt(const float* __restrict__ in, __bf16* __restrict__ out, int n) {
    int i = (blockIdx.x * 256 + threadIdx.x) * 8;
    if (i >= n) return;
    float4 a = *(const float4*)(in + i);
    float4 b = *(const float4*)(in + i + 4);
    bf16x8 v;
    v[0] = (__bf16)a.x; v[1] = (__bf16)a.y; v[2] = (__bf16)a.z; v[3] = (__bf16)a.w;
    v[4] = (__bf16)b.x; v[5] = (__bf16)b.y; v[6] = (__bf16)b.z; v[7] = (__bf16)b.w;
    *(bf16x8*)(out + i) = v;
}

// all four weight transposes in ONE dispatch (fp32 [R][C] -> bf16 [C][R])
__global__ __launch_bounds__(256) void k_trans_all(
    const float* __restrict__ Ws1, const float* __restrict__ Wg1,
    const float* __restrict__ Ws2, const float* __restrict__ Wg2,
    __bf16* __restrict__ W1t, __bf16* __restrict__ W2t)
{
    __shared__ float tile[64][65];
    int idx = blockIdx.x;
    const float* in; __bf16* out; int C, cshift, tile_i;
    const size_t HD = (size_t)Hm * Dm;
    if (idx < 1792) {
        int bank = idx >> 7; tile_i = idx & 127;
        C = Hm; cshift = 4;
        in = (bank < 2) ? (Ws1 + (size_t)bank * HD) : (Wg1 + (size_t)(bank - 2) * HD);
        out = W1t + (size_t)bank * HD;
    } else {
        idx -= 1792;
        int bank = idx >> 7; tile_i = idx & 127;
        C = Dm; cshift = 3;
        in = (bank < 2) ? (Ws2 + (size_t)bank * HD) : (Wg2 + (size_t)(bank - 2) * HD);
        out = W2t + (size_t)bank * HD;
    }
    const int r0 = (tile_i >> cshift) * 64;
    const int c0 = (tile_i & ((1 << cshift) - 1)) * 64;
    const int R = (C == Hm) ? Dm : Hm;
    const int t = threadIdx.x;
    {
        int r = t >> 2, cs = (t & 3) * 16;
        const float4* src = (const float4*)(in + (size_t)(r0 + r) * C + c0 + cs);
        #pragma unroll
        for (int i = 0; i < 4; i++) {
            float4 v = src[i];
            tile[r][cs + i * 4 + 0] = v.x;
            tile[r][cs + i * 4 + 1] = v.y;
            tile[r][cs + i * 4 + 2] = v.z;
            tile[r][cs + i * 4 + 3] = v.w;
        }
    }
    __syncthreads();
    {
        int c = t >> 2, rs = (t & 3) * 16;
        __bf16* dst = out + (size_t)(c0 + c) * R + r0 + rs;
        bf16x8 v0, v1;
        #pragma unroll
        for (int i = 0; i < 8; i++) v0[i] = (__bf16)tile[rs + i][c];
        #pragma unroll
        for (int i = 0; i < 8; i++) v1[i] = (__bf16)tile[rs + 8 + i][c];
        *(bf16x8*)dst = v0;
        *(bf16x8*)(dst + 8) = v1;
    }
}

// ---------------------------------------------------------------- fused FFN GEMM
// 128x128 tile, BK=32, double-buffered LDS (16KB/buf pair), prefetch across
// barrier. 128B LDS lines pack two 64B k-rows; XOR swizzle g8=(half*4+quad)^l
// keeps fragment ds_read_b128 at the 8-cycle structural floor (no conflicts).
// LDS 33KB -> 4 blocks/CU.
template<int KDIM, int NDIM, bool RELU>
__global__ __launch_bounds__(256) void k_ffn(
    const __bf16* __restrict__ Abase, int AstrTok, int AeStr,
    const __bf16* __restrict__ Wt,
    const float* __restrict__ bsh, const float* __restrict__ bgr,
    const int* __restrict__ counts, const int* __restrict__ lists,
    const int2* __restrict__ table, const int* __restrict__ ntot,
    __bf16* __restrict__ Obase, int OstrTok, int OeStr)
{
    constexpr int NT = NDIM / 128;
    constexpr int KT = KDIM / 32;
    const int mt = blockIdx.x / NT;
    if (mt >= *ntot) return;
    const int nt = blockIdx.x % NT;
    const int2 te = table[mt];
    const int bank = te.x, m0 = te.y;
    const int cnt = (bank < 2) ? NTOK : counts[(bank - 2) >> 1];
    const int n0 = nt * 128;
    const int e = (bank < 2) ? bank : 2 + ((bank - 2) & 1);

    __shared__ int tok_lds[128];
    __shared__ __align__(16) __bf16 A_lds[2][128 * 32];
    __shared__ __align__(16) __bf16 B_lds[2][128 * 32];

    const int t = threadIdx.x;
    if (t < 128) {
        int idx = m0 + t;
        int tok = -1;
        if (idx < cnt) tok = (bank < 2) ? idx : lists[((bank - 2) >> 1) * NTOK + idx];
        tok_lds[t] = tok;
    }
    __syncthreads();

    const int w = t >> 6, lane = t & 63;

    // staging: thread t covers slots S=t and S=t+256; slot S = line l (128B),
    // granule g8; content = row 2l+(s>>2), 16B k-granule s&3 with s=g8^(l&7)
    const __bf16* aG[2]; const __bf16* bG[2];
    #pragma unroll
    for (int r2 = 0; r2 < 2; r2++) {
        int S = t + r2 * 256;
        int l = S >> 3, g8 = S & 7;
        int s = g8 ^ (l & 7);
        int row = 2 * l + (s >> 2), gk = s & 3;
        int tok = tok_lds[row]; if (tok < 0) tok = 0;
        aG[r2] = Abase + (size_t)tok * AstrTok + (size_t)e * AeStr + gk * 8;
        bG[r2] = Wt + (size_t)bank * NDIM * KDIM + (size_t)(n0 + row) * KDIM + gk * 8;
    }

    // fragment offsets: addr = l*64 + g8*8 elems, l=row>>1, g8=(half*4+quad)^(l&7)
    const int col = lane & 15, quad = lane >> 4;
    const int mh = (w >> 1) * 64, nh = (w & 1) * 64;
    const int c2 = col >> 1, half = col & 1;
    const int g8r = ((half << 2) + quad) ^ c2;
    int aoff[4], boff[4];
    #pragma unroll
    for (int f = 0; f < 4; f++) {
        aoff[f] = ((mh >> 1) + f * 8 + c2) * 64 + g8r * 8;
        boff[f] = ((nh >> 1) + f * 8 + c2) * 64 + g8r * 8;
    }

    floatx4 acc[4][4] = {};

    // prologue: stage k-tile 0 into buf 0
    #pragma unroll
    for (int r2 = 0; r2 < 2; r2++) {
        async16(aG[r2], &A_lds[0][w * 512 + r2 * 2048]);
        async16(bG[r2], &B_lds[0][w * 512 + r2 * 2048]);
    }
    __syncthreads();

    #pragma unroll 2
    for (int kt = 0; kt < KT; kt++) {
        const int p = kt & 1, q = p ^ 1;
        if (kt + 1 < KT) {
            const int ko = (kt + 1) * 32;
            #pragma unroll
            for (int r2 = 0; r2 < 2; r2++) {
                async16(aG[r2] + ko, &A_lds[q][w * 512 + r2 * 2048]);
                async16(bG[r2] + ko, &B_lds[q][w * 512 + r2 * 2048]);
            }
        }
        bf16x8 af[4], bv[4];
        #pragma unroll
        for (int f = 0; f < 4; f++) {
            af[f] = *(const bf16x8*)&A_lds[p][aoff[f]];
            bv[f] = *(const bf16x8*)&B_lds[p][boff[f]];
        }
        #pragma unroll
        for (int mf = 0; mf < 4; mf++)
            #pragma unroll
            for (int nf = 0; nf < 4; nf++)
                acc[mf][nf] = __builtin_amdgcn_mfma_f32_16x16x32_bf16(
                    af[mf], bv[nf], acc[mf][nf], 0, 0, 0);
        __syncthreads();
    }

    const float* bp = (bank < 2) ? (bsh + (size_t)bank * NDIM)
                                 : (bgr + (size_t)(bank - 2) * NDIM);
    float bias[4];
    #pragma unroll
    for (int nf = 0; nf < 4; nf++) bias[nf] = bp[n0 + nh + nf * 16 + col];

    #pragma unroll
    for (int mf = 0; mf < 4; mf++) {
        #pragma unroll
        for (int r = 0; r < 4; r++) {
            int m = mh + mf * 16 + quad * 4 + r;
            int tok = tok_lds[m];
            if (tok >= 0) {
                __bf16* orow = Obase + (size_t)tok * OstrTok + (size_t)e * OeStr + n0 + nh + col;
                #pragma unroll
                for (int nf = 0; nf < 4; nf++) {
                    float v = acc[mf][nf][r] + bias[nf];
                    if (RELU) v = fmaxf(v, 0.0f);
                    orow[nf * 16] = (__bf16)v;
                }
            }
        }
    }
}

// ---------------------------------------------------------------- fused gate+combine
// wave-per-token. Butterfly reduce leaves full logit sums in ALL lanes, so
// softmax is computed per-lane (no LDS round-trip) and combine proceeds
// directly: out[k][tok][d] = sum_e w[k][e] * eo[tok][e][d].
__global__ __launch_bounds__(256) void k_gc(
    const float* __restrict__ x, const float* __restrict__ cond_emb,
    const int* __restrict__ gids, const float* __restrict__ gW,
    const float* __restrict__ gb, const __bf16* __restrict__ eo,
    float* __restrict__ out)
{
    __shared__ float gwl[544 * 13];
    const int t = threadIdx.x;
    for (int i = t; i < 544 * 12; i += 256) {
        int f = i / 12, j = i - f * 12;
        gwl[f * 13 + j] = gW[((size_t)(j >> 2) * 544 + f) * 4 + (j & 3)];
    }
    __syncthreads();

    const int wave = t >> 6, lane = t & 63;
    const int tok = blockIdx.x * 4 + wave;
    const int gid = gids[tok];
    const float* xr = x + (size_t)tok * Dm;

    float a[12] = {};
    #pragma unroll
    for (int j = 0; j < 8; j++) {
        float xv = xr[j * 64 + lane];
        const float* base = &gwl[(j * 64 + lane) * 13];
        #pragma unroll
        for (int jj = 0; jj < 12; jj++) a[jj] += xv * base[jj];
    }
    if (lane < Cm) {
        float xv = cond_emb[gid * Cm + lane];
        const float* base = &gwl[(Dm + lane) * 13];
        #pragma unroll
        for (int jj = 0; jj < 12; jj++) a[jj] += xv * base[jj];
    }
    #pragma unroll
    for (int off = 1; off < 64; off <<= 1)
        #pragma unroll
        for (int jj = 0; jj < 12; jj++)
            a[jj] += __shfl_xor(a[jj], off, 64);

    float w[Km][Em];
    #pragma unroll
    for (int k = 0; k < Km; k++) {
        float v0 = a[k * 4 + 0] + gb[k * 4 + 0];
        float v1 = a[k * 4 + 1] + gb[k * 4 + 1];
        float v2 = a[k * 4 + 2] + gb[k * 4 + 2];
        float v3 = a[k * 4 + 3] + gb[k * 4 + 3];
        float m = fmaxf(fmaxf(v0, v1), fmaxf(v2, v3));
        float e0 = __expf(v0 - m), e1 = __expf(v1 - m), e2 = __expf(v2 - m), e3 = __expf(v3 - m);
        float inv = 1.0f / (e0 + e1 + e2 + e3);
        w[k][0] = e0 * inv; w[k][1] = e1 * inv; w[k][2] = e2 * inv; w[k][3] = e3 * inv;
    }

    const int d0 = lane * 8;
    const __bf16* ep = eo + (size_t)tok * Em * Dm;
    float o[Km][8] = {};
    #pragma unroll
    for (int e = 0; e < Em; e++) {
        bf16x8 v = *(const bf16x8*)(ep + (size_t)e * Dm + d0);
        float f[8];
        #pragma unroll
        for (int i = 0; i < 8; i++) f[i] = (float)v[i];
        #pragma unroll
        for (int k = 0; k < Km; k++)
            #pragma unroll
            for (int i = 0; i < 8; i++) o[k][i] += w[k][e] * f[i];
    }
    #pragma unroll
    for (int k = 0; k < Km; k++) {
        float* op = out + ((size_t)k * NTOK + tok) * Dm + d0;
        *(float4*)op = make_float4(o[k][0], o[k][1], o[k][2], o[k][3]);
        *(float4*)(op + 4) = make_float4(o[k][4], o[k][5], o[k][6], o[k][7]);
    }
}

// ---------------------------------------------------------------- launch

static inline size_t align256(size_t v) { return (v + 255) & ~(size_t)255; }

extern "C" void kernel_launch(void* const* d_in, const int* in_sizes, int n_in,
                              void* d_out, int out_size, void* d_ws, size_t ws_size,
                              hipStream_t stream) {
    const float* x        = (const float*)d_in[0];
    const int*   ids      = (const int*)d_in[1];
    const int*   e2g      = (const int*)d_in[2];
    const float* Ws1      = (const float*)d_in[3];
    const float* bs1      = (const float*)d_in[4];
    const float* Ws2      = (const float*)d_in[5];
    const float* bs2      = (const float*)d_in[6];
    const float* Wg1      = (const float*)d_in[7];
    const float* bg1      = (const float*)d_in[8];
    const float* Wg2      = (const float*)d_in[9];
    const float* bg2      = (const float*)d_in[10];
    const float* cond_emb = (const float*)d_in[11];
    const float* gate_W   = (const float*)d_in[12];
    const float* gate_b   = (const float*)d_in[13];
    float* out = (float*)d_out;

    char* ws = (char*)d_ws;
    size_t off = 0;
    const size_t HD = (size_t)Hm * Dm;

    __bf16* xb  = (__bf16*)(ws + off); off = align256(off + (size_t)NTOK * Dm * 2);
    __bf16* W1t = (__bf16*)(ws + off); off = align256(off + (size_t)NBANK * HD * 2);
    __bf16* W2t = (__bf16*)(ws + off); off = align256(off + (size_t)NBANK * HD * 2);
    __bf16* hb  = (__bf16*)(ws + off); off = align256(off + (size_t)NTOK * Em * Hm * 2);
    __bf16* eo  = (__bf16*)(ws + off); off = align256(off + (size_t)NTOK * Em * Dm * 2);
    int*    gids   = (int*)(ws + off); off = align256(off + (size_t)NTOK * 4);
    int*    counts = (int*)(ws + off); off = align256(off + 256);
    int*    lists  = (int*)(ws + off); off = align256(off + (size_t)NGm * NTOK * 4);
    int2*   table  = (int2*)(ws + off); off = align256(off + (size_t)MAXMT * 8);
    int*    ntot   = (int*)(ws + off);  off = align256(off + 256);
    (void)ws_size; (void)n_in; (void)in_sizes; (void)out_size;

    // 1) bucket + tile plan
    k_prep<<<1, 1024, 0, stream>>>(ids, e2g, gids, counts, lists, table, ntot);

    // 2) conversions
    k_cvt<<<(NTOK * Dm) / (8 * 256), 256, 0, stream>>>(x, xb, NTOK * Dm);
    k_trans_all<<<3584, 256, 0, stream>>>(Ws1, Wg1, Ws2, Wg2, W1t, W2t);

    // 3) FFN layer 1: x @ W1t -> relu -> hb (bf16)
    k_ffn<Dm, Hm, true><<<MAXMT * (Hm / 128), 256, 0, stream>>>(
        xb, Dm, 0, W1t, bs1, bg1, counts, lists, table, ntot,
        hb, Em * Hm, Hm);

    // 4) FFN layer 2: hb @ W2t -> eo (bf16)
    k_ffn<Hm, Dm, false><<<MAXMT * (Dm / 128), 256, 0, stream>>>(
        hb, Em * Hm, Hm, W2t, bs2, bg2, counts, lists, table, ntot,
        eo, Em * Dm, Dm);

    // 5) fused gate + combine
    k_gc<<<NTOK / 4, 256, 0, stream>>>(x, cond_emb, gids, gate_W, gate_b, eo, out);
}